// Round 14
// baseline (458.359 us; speedup 1.0000x reference)
//
#include <hip/hip_runtime.h>
#include <hip/hip_bf16.h>
#include <stdint.h>

#define N_NODES 50000
#define E_EDGES 800000

typedef short s16x8 __attribute__((ext_vector_type(8)));
typedef float f32x4 __attribute__((ext_vector_type(4)));

__device__ __forceinline__ float bf2f(unsigned int u) {
    return __uint_as_float(u << 16);
}
__device__ __forceinline__ unsigned short f2bf(float f) {
    unsigned int u = __float_as_uint(f);
    unsigned int r = (u + 0x7FFFu + ((u >> 16) & 1u)) >> 16;
    return (unsigned short)r;
}
__device__ __forceinline__ void split_bf(float v, unsigned short& hi, unsigned short& lo) {
    hi = f2bf(v);
    lo = f2bf(v - bf2f(hi));
}
#define MFMA(a, b, c) __builtin_amdgcn_mfma_f32_16x16x32_bf16((a), (b), (c), 0, 0, 0)

// ---------------- CSR construction (unchanged, R11) ----------------

__global__ void hist_deg(const int* __restrict__ dst, int* __restrict__ deg) {
    int e = blockIdx.x * blockDim.x + threadIdx.x;
    if (e >= E_EDGES) return;
    atomicAdd(&deg[dst[e]], 1);
}

__global__ __launch_bounds__(1024) void scan1(const int* __restrict__ deg,
                                              int* __restrict__ lexcl,
                                              int* __restrict__ btot) {
    __shared__ int wsum[16];
    int gid = blockIdx.x * 1024 + threadIdx.x;
    int lane = threadIdx.x & 63, wid = threadIdx.x >> 6;
    int v = (gid < N_NODES) ? deg[gid] : 0;
    int x = v;
#pragma unroll
    for (int off = 1; off < 64; off <<= 1) {
        int t = __shfl_up(x, off);
        if (lane >= off) x += t;
    }
    if (lane == 63) wsum[wid] = x;
    __syncthreads();
    if (wid == 0 && lane < 16) {
        int w = wsum[lane];
#pragma unroll
        for (int off = 1; off < 16; off <<= 1) {
            int t = __shfl_up(w, off);
            if (lane >= off) w += t;
        }
        wsum[lane] = w;
    }
    __syncthreads();
    int excl = x - v + (wid ? wsum[wid - 1] : 0);
    if (gid < N_NODES) lexcl[gid] = excl;
    if (threadIdx.x == 0) btot[blockIdx.x] = wsum[15];
}

__global__ void scan2(const int* __restrict__ btot, int* __restrict__ bbase,
                      int nb) {
    int lane = threadIdx.x;
    int v = (lane < nb) ? btot[lane] : 0;
    int x = v;
#pragma unroll
    for (int off = 1; off < 64; off <<= 1) {
        int t = __shfl_up(x, off);
        if (lane >= off) x += t;
    }
    if (lane < nb) bbase[lane] = x - v;
}

__global__ void scan3(const int* __restrict__ lexcl, const int* __restrict__ bbase,
                      int* __restrict__ rowptr, int* __restrict__ cursor) {
    int gid = blockIdx.x * blockDim.x + threadIdx.x;
    if (gid < N_NODES) {
        int r = lexcl[gid] + bbase[gid >> 10];
        rowptr[gid] = r;
        cursor[gid] = r;
    }
    if (gid == 0) rowptr[N_NODES] = E_EDGES;
}

__global__ void fill_csr(const int* __restrict__ src, const int* __restrict__ dst,
                         int* __restrict__ cursor, unsigned short* __restrict__ perm) {
    int e = blockIdx.x * blockDim.x + threadIdx.x;
    if (e >= E_EDGES) return;
    int d = dst[e];
    int pos = atomicAdd(&cursor[d], 1);
    perm[pos] = (unsigned short)src[e];
}

// ---------------- Aggregation (R5/R11 shape — best measured) ----------------
__global__ __launch_bounds__(256) void gather_agg(
    const float* __restrict__ feat,
    const int* __restrict__ rowptr,
    const unsigned short* __restrict__ perm,
    float* __restrict__ out) {
    int node = (blockIdx.x * 256 + threadIdx.x) >> 6;
    if (node >= N_NODES) return;
    int lane = threadIdx.x & 63;
    const float2* fv = (const float2*)feat;
    float2 acc = fv[(size_t)node * 64 + lane];
    int beg = rowptr[node], end = rowptr[node + 1];
    for (int base = beg; base < end; base += 64) {
        int cnt = end - base; if (cnt > 64) cnt = 64;
        int pv = (base + lane < end) ? (int)perm[base + lane] : 0;
        int j = 0;
        for (; j + 1 < cnt; j += 2) {
            int s0 = __shfl(pv, j);
            int s1 = __shfl(pv, j + 1);
            float2 v0 = fv[(size_t)s0 * 64 + lane];
            float2 v1 = fv[(size_t)s1 * 64 + lane];
            acc.x += v0.x + v1.x;
            acc.y += v0.y + v1.y;
        }
        if (j < cnt) {
            int s = __shfl(pv, j);
            float2 v = fv[(size_t)s * 64 + lane];
            acc.x += v.x;
            acc.y += v.y;
        }
    }
    ((float2*)out)[(size_t)node * 64 + lane] = acc;
}

// ---- Weight pre-split (fused) ----
__device__ __forceinline__ void prep_one(const float* __restrict__ W,
                                         unsigned short* __restrict__ Whi,
                                         unsigned short* __restrict__ Wlo,
                                         int K, int F, int Fpad, int i) {
    int S = K / 32, T = Fpad / 16;
    int total = T * S * 64;
    if (i >= total) return;
    int lane = i & 63;
    int s = (i >> 6) % S;
    int t = (i >> 6) / S;
    int col = t * 16 + (lane & 15);
    int k0 = s * 32 + (lane >> 4) * 8;
    s16x8 vh, vl;
#pragma unroll
    for (int j = 0; j < 8; j++) {
        float w = (col < F) ? W[(size_t)(k0 + j) * F + col] : 0.f;
        unsigned short h, l;
        split_bf(w, h, l);
        vh[j] = (short)h;
        vl[j] = (short)l;
    }
    *(s16x8*)(Whi + (size_t)i * 8) = vh;
    *(s16x8*)(Wlo + (size_t)i * 8) = vl;
}

__global__ void prep_all(const float* W1, const float* W2, const float* W3,
                         const float* W4, const float* Wl,
                         unsigned short* W1h, unsigned short* W1l,
                         unsigned short* W2h, unsigned short* W2l,
                         unsigned short* W3h, unsigned short* W3l,
                         unsigned short* W4h, unsigned short* W4l,
                         unsigned short* Wlh, unsigned short* Wll) {
    int b = blockIdx.x, t = threadIdx.x;
    if (b < 8)       prep_one(W1, W1h, W1l, 128, 128, 128, b * 256 + t);
    else if (b < 16) prep_one(W2, W2h, W2l, 128, 128, 128, (b - 8) * 256 + t);
    else if (b < 32) prep_one(W3, W3h, W3l, 128, 256, 256, (b - 16) * 256 + t);
    else if (b < 64) prep_one(W4, W4h, W4l, 256, 256, 256, (b - 32) * 256 + t);
    else             prep_one(Wl, Wlh, Wll, 256, 40, 48, (b - 64) * 256 + t);
}

// ================== Fused MLP kernels ==================
// Per-wave LDS fragment buffer: C-layout epilogue values written in exact
// A-fragment order (lane' = (k_local>>3)*16 + quad*4 + q, elem j = k_local&7),
// read back as one conflict-free 16B ds_read_b128 per fragment. LDS is
// strictly per-wave: no __syncthreads needed (in-wave DS ordering + lgkmcnt).

// Layer 1: h1b = relu( relu(A@W1+b1) @ W2 + b2 ),  A fp32 [N,128] -> fp32 [N,128]
__global__ __launch_bounds__(256) void fused_mlp1(
    const float* __restrict__ A,
    const unsigned short* __restrict__ W1h, const unsigned short* __restrict__ W1l,
    const float* __restrict__ b1,
    const unsigned short* __restrict__ W2h, const unsigned short* __restrict__ W2l,
    const float* __restrict__ b2,
    float* __restrict__ O) {
    __shared__ unsigned short Fh[4][2][64][8];
    __shared__ unsigned short Fl[4][2][64][8];
    int wave = threadIdx.x >> 6, lane = threadIdx.x & 63;
    int row0 = blockIdx.x * 64 + wave * 16;
    if (row0 >= N_NODES) return;
    int lm = lane & 15, quad = lane >> 4;

    // hoist A row (K=128) into split registers (split once, reuse 4x)
    s16x8 ah[4], al[4];
#pragma unroll
    for (int s = 0; s < 4; s++) {
        const float* ap = A + (size_t)(row0 + lm) * 128 + s * 32 + quad * 8;
        float4 x0 = *(const float4*)ap;
        float4 x1 = *(const float4*)(ap + 4);
        float v[8] = {x0.x, x0.y, x0.z, x0.w, x1.x, x1.y, x1.z, x1.w};
#pragma unroll
        for (int j = 0; j < 8; j++) {
            unsigned short h, l;
            split_bf(v[j], h, l);
            ah[s][j] = (short)h;
            al[s][j] = (short)l;
        }
    }

    f32x4 acc2[8];
#pragma unroll
    for (int t = 0; t < 8; t++) { f32x4 z = {0.f,0.f,0.f,0.f}; acc2[t] = z; }

#pragma unroll
    for (int c = 0; c < 4; c++) {          // 32-col chunk of h1; also s2=c for W2
        f32x4 acc1[2];
#pragma unroll
        for (int t = 0; t < 2; t++) { f32x4 z = {0.f,0.f,0.f,0.f}; acc1[t] = z; }
#pragma unroll
        for (int s = 0; s < 4; s++)
#pragma unroll
            for (int t = 0; t < 2; t++) {
                int tg = c * 2 + t;
                size_t fi = (size_t)((tg * 4 + s) * 64 + lane) * 8;
                s16x8 bh = *(const s16x8*)(W1h + fi);
                s16x8 bl = *(const s16x8*)(W1l + fi);
                acc1[t] = MFMA(ah[s], bh, acc1[t]);
                acc1[t] = MFMA(al[s], bh, acc1[t]);
                acc1[t] = MFMA(ah[s], bl, acc1[t]);
            }
        int slot = c & 1;
#pragma unroll
        for (int t = 0; t < 2; t++) {
            int tg = c * 2 + t;
            float bv = b1[tg * 16 + lm];
            int kl = t * 16 + lm;
            int lp = (kl >> 3) * 16 + quad * 4;
            int jj = kl & 7;
#pragma unroll
            for (int q = 0; q < 4; q++) {
                float vv = fmaxf(acc1[t][q] + bv, 0.f);
                unsigned short h, l;
                split_bf(vv, h, l);
                Fh[wave][slot][lp + q][jj] = h;
                Fl[wave][slot][lp + q][jj] = l;
            }
        }
        s16x8 a2h = *(const s16x8*)Fh[wave][slot][lane];
        s16x8 a2l = *(const s16x8*)Fl[wave][slot][lane];
#pragma unroll
        for (int t2 = 0; t2 < 8; t2++) {
            size_t fi = (size_t)((t2 * 4 + c) * 64 + lane) * 8;
            s16x8 bh = *(const s16x8*)(W2h + fi);
            s16x8 bl = *(const s16x8*)(W2l + fi);
            acc2[t2] = MFMA(a2h, bh, acc2[t2]);
            acc2[t2] = MFMA(a2l, bh, acc2[t2]);
            acc2[t2] = MFMA(a2h, bl, acc2[t2]);
        }
    }

    int orow = row0 + quad * 4;
#pragma unroll
    for (int t2 = 0; t2 < 8; t2++) {
        int col = t2 * 16 + lm;
        float bv = b2[col];
#pragma unroll
        for (int q = 0; q < 4; q++)
            O[(size_t)(orow + q) * 128 + col] = fmaxf(acc2[t2][q] + bv, 0.f);
    }
}

// Layer 2 + final: out = relu(relu(A@W3+b3)@W4+b4)@Wl + bl,  A fp32 [N,128] -> fp32 [N,40]
__global__ __launch_bounds__(256) void fused_mlp2(
    const float* __restrict__ A,
    const unsigned short* __restrict__ W3h, const unsigned short* __restrict__ W3l,
    const float* __restrict__ b3,
    const unsigned short* __restrict__ W4h, const unsigned short* __restrict__ W4l,
    const float* __restrict__ b4,
    const unsigned short* __restrict__ Wlh, const unsigned short* __restrict__ Wll,
    const float* __restrict__ bl,
    float* __restrict__ out) {
    __shared__ unsigned short Fh[4][2][64][8];
    __shared__ unsigned short Fl[4][2][64][8];
    int wave = threadIdx.x >> 6, lane = threadIdx.x & 63;
    int row0 = blockIdx.x * 64 + wave * 16;
    if (row0 >= N_NODES) return;
    int lm = lane & 15, quad = lane >> 4;

    s16x8 ah[4], al[4];
#pragma unroll
    for (int s = 0; s < 4; s++) {
        const float* ap = A + (size_t)(row0 + lm) * 128 + s * 32 + quad * 8;
        float4 x0 = *(const float4*)ap;
        float4 x1 = *(const float4*)(ap + 4);
        float v[8] = {x0.x, x0.y, x0.z, x0.w, x1.x, x1.y, x1.z, x1.w};
#pragma unroll
        for (int j = 0; j < 8; j++) {
            unsigned short h, l;
            split_bf(v[j], h, l);
            ah[s][j] = (short)h;
            al[s][j] = (short)l;
        }
    }

    f32x4 acc2[16];
#pragma unroll
    for (int t = 0; t < 16; t++) { f32x4 z = {0.f,0.f,0.f,0.f}; acc2[t] = z; }

    // Stage A (128->256, W3) chunk-interleaved with Stage B (256->256, W4)
#pragma unroll
    for (int c = 0; c < 8; c++) {
        f32x4 acc1[2];
#pragma unroll
        for (int t = 0; t < 2; t++) { f32x4 z = {0.f,0.f,0.f,0.f}; acc1[t] = z; }
#pragma unroll
        for (int s = 0; s < 4; s++)
#pragma unroll
            for (int t = 0; t < 2; t++) {
                int tg = c * 2 + t;
                size_t fi = (size_t)((tg * 4 + s) * 64 + lane) * 8;
                s16x8 bh = *(const s16x8*)(W3h + fi);
                s16x8 bl = *(const s16x8*)(W3l + fi);
                acc1[t] = MFMA(ah[s], bh, acc1[t]);
                acc1[t] = MFMA(al[s], bh, acc1[t]);
                acc1[t] = MFMA(ah[s], bl, acc1[t]);
            }
        int slot = c & 1;
#pragma unroll
        for (int t = 0; t < 2; t++) {
            int tg = c * 2 + t;
            float bv = b3[tg * 16 + lm];
            int kl = t * 16 + lm;
            int lp = (kl >> 3) * 16 + quad * 4;
            int jj = kl & 7;
#pragma unroll
            for (int q = 0; q < 4; q++) {
                float vv = fmaxf(acc1[t][q] + bv, 0.f);
                unsigned short h, l;
                split_bf(vv, h, l);
                Fh[wave][slot][lp + q][jj] = h;
                Fl[wave][slot][lp + q][jj] = l;
            }
        }
        s16x8 a2h = *(const s16x8*)Fh[wave][slot][lane];
        s16x8 a2l = *(const s16x8*)Fl[wave][slot][lane];
#pragma unroll
        for (int t2 = 0; t2 < 16; t2++) {
            size_t fi = (size_t)((t2 * 8 + c) * 64 + lane) * 8;
            s16x8 bh = *(const s16x8*)(W4h + fi);
            s16x8 bl = *(const s16x8*)(W4l + fi);
            acc2[t2] = MFMA(a2h, bh, acc2[t2]);
            acc2[t2] = MFMA(a2l, bh, acc2[t2]);
            acc2[t2] = MFMA(a2h, bl, acc2[t2]);
        }
    }

    // Stage C (256->40, Wl), chunked over acc2
    f32x4 acc3[3];
#pragma unroll
    for (int t = 0; t < 3; t++) { f32x4 z = {0.f,0.f,0.f,0.f}; acc3[t] = z; }
#pragma unroll
    for (int c = 0; c < 8; c++) {
        int slot = c & 1;
#pragma unroll
        for (int t = 0; t < 2; t++) {
            int tg = c * 2 + t;
            float bv = b4[tg * 16 + lm];
            int kl = t * 16 + lm;
            int lp = (kl >> 3) * 16 + quad * 4;
            int jj = kl & 7;
#pragma unroll
            for (int q = 0; q < 4; q++) {
                float vv = fmaxf(acc2[tg][q] + bv, 0.f);
                unsigned short h, l;
                split_bf(vv, h, l);
                Fh[wave][slot][lp + q][jj] = h;
                Fl[wave][slot][lp + q][jj] = l;
            }
        }
        s16x8 a3h = *(const s16x8*)Fh[wave][slot][lane];
        s16x8 a3l = *(const s16x8*)Fl[wave][slot][lane];
#pragma unroll
        for (int t3 = 0; t3 < 3; t3++) {
            size_t fi = (size_t)((t3 * 8 + c) * 64 + lane) * 8;
            s16x8 bh = *(const s16x8*)(Wlh + fi);
            s16x8 bl = *(const s16x8*)(Wll + fi);
            acc3[t3] = MFMA(a3h, bh, acc3[t3]);
            acc3[t3] = MFMA(a3l, bh, acc3[t3]);
            acc3[t3] = MFMA(a3h, bl, acc3[t3]);
        }
    }

    int orow = row0 + quad * 4;
#pragma unroll
    for (int t3 = 0; t3 < 3; t3++) {
        int col = t3 * 16 + lm;
        if (col < 40) {
            float bv = bl[col];
#pragma unroll
            for (int q = 0; q < 4; q++)
                out[(size_t)(orow + q) * 40 + col] = acc3[t3][q] + bv;
        }
    }
}

extern "C" void kernel_launch(void* const* d_in, const int* in_sizes, int n_in,
                              void* d_out, int out_size, void* d_ws, size_t ws_size,
                              hipStream_t stream) {
    const float* x  = (const float*)d_in[0];
    const int* ei   = (const int*)d_in[1];
    const float* W1 = (const float*)d_in[2];
    const float* b1 = (const float*)d_in[3];
    const float* W2 = (const float*)d_in[4];
    const float* b2 = (const float*)d_in[5];
    const float* W3 = (const float*)d_in[6];
    const float* b3 = (const float*)d_in[7];
    const float* W4 = (const float*)d_in[8];
    const float* b4 = (const float*)d_in[9];
    const float* Wl = (const float*)d_in[10];
    const float* bl = (const float*)d_in[11];
    float* out = (float*)d_out;

    const int* src = ei;
    const int* dst = ei + E_EDGES;

    // ---- Workspace ----
    char* ws = (char*)d_ws;
    const size_t P = (size_t)N_NODES * 128 * 4;   // 25.6e6 B per [N,128] fp32
    float* hF   = (float*)ws;          // region A: gather1 out; reused as hF2
    float* hF2  = (float*)ws;
    float* h1b  = (float*)(ws + P);    // region B: fused1 out
    size_t off = 2 * P;
    unsigned short* W1h = (unsigned short*)(ws + off); off += 16384 * 2;
    unsigned short* W1l = (unsigned short*)(ws + off); off += 16384 * 2;
    unsigned short* W2h = (unsigned short*)(ws + off); off += 16384 * 2;
    unsigned short* W2l = (unsigned short*)(ws + off); off += 16384 * 2;
    unsigned short* W3h = (unsigned short*)(ws + off); off += 32768 * 2;
    unsigned short* W3l = (unsigned short*)(ws + off); off += 32768 * 2;
    unsigned short* W4h = (unsigned short*)(ws + off); off += 65536 * 2;
    unsigned short* W4l = (unsigned short*)(ws + off); off += 65536 * 2;
    unsigned short* Wlh = (unsigned short*)(ws + off); off += 12288 * 2;
    unsigned short* Wll = (unsigned short*)(ws + off); off += 12288 * 2;
    off = (off + 255) & ~(size_t)255;
    int* deg    = (int*)(ws + off); off += (size_t)(N_NODES + 1) * 4;
    int* cursor = (int*)(ws + off); off += (size_t)(N_NODES + 1) * 4;
    int* rowptr = (int*)(ws + off); off += (size_t)(N_NODES + 1) * 4;
    unsigned short* perm = (unsigned short*)(ws + off); off += (size_t)E_EDGES * 2;
    off = (off + 255) & ~(size_t)255;
    int* lexcl  = (int*)(ws + off); off += (size_t)N_NODES * 4;
    int* btot   = (int*)(ws + off); off += 64 * 4;
    int* bbase  = (int*)(ws + off); off += 64 * 4;
    (void)ws_size; (void)in_sizes; (void)n_in; (void)out_size;

    const int NB = (N_NODES + 1023) / 1024;

    // ---- CSR build ----
    (void)hipMemsetAsync(deg, 0, (size_t)(N_NODES + 1) * 4, stream);
    hist_deg<<<(E_EDGES + 255) / 256, 256, 0, stream>>>(dst, deg);
    scan1<<<NB, 1024, 0, stream>>>(deg, lexcl, btot);
    scan2<<<1, 64, 0, stream>>>(btot, bbase, NB);
    scan3<<<(N_NODES + 255) / 256, 256, 0, stream>>>(lexcl, bbase, rowptr, cursor);
    fill_csr<<<(E_EDGES + 255) / 256, 256, 0, stream>>>(src, dst, cursor, perm);

    // ---- Weight pre-split ----
    prep_all<<<70, 256, 0, stream>>>(W1, W2, W3, W4, Wl,
                                     W1h, W1l, W2h, W2l, W3h, W3l,
                                     W4h, W4l, Wlh, Wll);

    const int aggBlocks = (N_NODES * 64 + 255) / 256;   // one wave per node
    const int mlpBlocks = (N_NODES + 63) / 64;          // 782

    // ---- Layer 1 ----
    gather_agg<<<aggBlocks, 256, 0, stream>>>(x, rowptr, perm, hF);
    fused_mlp1<<<mlpBlocks, 256, 0, stream>>>(hF, W1h, W1l, b1, W2h, W2l, b2, h1b);

    // ---- Layer 2 + final linear ----
    gather_agg<<<aggBlocks, 256, 0, stream>>>(h1b, rowptr, perm, hF2);
    fused_mlp2<<<mlpBlocks, 256, 0, stream>>>(hF2, W3h, W3l, b3, W4h, W4l, b4,
                                              Wlh, Wll, bl, out);
}